// Round 13
// baseline (158.384 us; speedup 1.0000x reference)
//
#include <hip/hip_runtime.h>

// Problem constants (N=4096 rows, D=2048 cols, T=0.5 -> 1/T = 2)
#define NR 4096
#define DD 2048
#define INV_T 2.0f
// fp4 path (gemm): a_n*64 ~ N(0,1.41) into e2m1 range ±6 (±4.2 sigma);
// MFMA acc = 4096*sim
#define QS4 64.0f
#define ACC4_TO_LOGIT (INV_T / (QS4 * QS4))  // 2/4096, gemm logits

typedef __attribute__((ext_vector_type(2))) float floatx2;
typedef __attribute__((ext_vector_type(4))) float floatx4;
typedef __attribute__((ext_vector_type(16))) float floatx16;
typedef __attribute__((ext_vector_type(4))) int int4v;
typedef __attribute__((ext_vector_type(8))) int int8v;
typedef __attribute__((ext_vector_type(4))) unsigned int uintx4;

static __device__ __forceinline__ void async_copy16(const void* g, void* lds) {
  __builtin_amdgcn_global_load_lds((const __attribute__((address_space(1))) void*)g,
                                   (__attribute__((address_space(3))) void*)lds,
                                   16, 0, 0);
}

// e2m1 encode of pre-scaled x: values {0,.5,1,1.5,2,3,4,6}, clamp at 6,
// round-to-nearest via midpoint thresholds. Returns 4-bit code.
static __device__ __forceinline__ unsigned int enc4(float x) {
  float u = fminf(fabsf(x), 6.0f);
  int c = (u >= 0.25f) + (u >= 0.75f) + (u >= 1.25f) + (u >= 1.75f) +
          (u >= 2.5f) + (u >= 3.5f) + (u >= 5.0f);
  return (unsigned)(c | (x < 0.f ? 8 : 0));
}

// HW fp4 pack (r20, kept: VALUBusy 22->8%). v_cvt_scalef32_pk_fp4_f32(old,
// s0, s1, scale, byte_sel): fp4(s0)->low nibble, fp4(s1)->high nibble of
// byte byte_sel. scale=1.0 identity; RNE; saturating (same as enc4 clamp).
#if __has_builtin(__builtin_amdgcn_cvt_scalef32_pk_fp4_f32)
static __device__ __forceinline__ unsigned int pack8_fp4(
    const float4& v0, const float4& v1, float s) {
  unsigned int w = 0;
  w = __builtin_amdgcn_cvt_scalef32_pk_fp4_f32(w, v0.x * s, v0.y * s, 1.0f, 0);
  w = __builtin_amdgcn_cvt_scalef32_pk_fp4_f32(w, v0.z * s, v0.w * s, 1.0f, 1);
  w = __builtin_amdgcn_cvt_scalef32_pk_fp4_f32(w, v1.x * s, v1.y * s, 1.0f, 2);
  w = __builtin_amdgcn_cvt_scalef32_pk_fp4_f32(w, v1.z * s, v1.w * s, 1.0f, 3);
  return w;
}
#else
static __device__ __forceinline__ unsigned int pack8_fp4(
    const float4& v0, const float4& v1, float s) {
  return enc4(v0.x * s)        | (enc4(v0.y * s) << 4)  |
         (enc4(v0.z * s) << 8) | (enc4(v0.w * s) << 12) |
         (enc4(v1.x * s) << 16)| (enc4(v1.y * s) << 20) |
         (enc4(v1.z * s) << 24)| (enc4(v1.w * s) << 28);
}
#endif

// ---------------------------------------------------------------------------
// Kernel 0: zero s_a|s_b (4096 floats). Separate dispatch: K1's colsum
// atomics would race with same-kernel zeroing.
// ---------------------------------------------------------------------------
__global__ __launch_bounds__(256) void zero_kernel(float* z) {
  #pragma unroll
  for (int i = 0; i < 4; i++)
    *(floatx4*)&z[4 * (threadIdx.x + 256 * i)] = floatx4{0.f, 0.f, 0.f, 0.f};
}

// ---------------------------------------------------------------------------
// Kernel 1: per-row L2 normalize + fused f32 column sums. UNCHANGED from r21
// (normalize declared at its empirical floor: 8 structural variants — TLP,
// access pattern, VGPR, atomics, spills, code size, per-wave MLP — all land
// at 40-42us. No further work on this kernel.)
// mat 0: fp4 a4 + colsum->s_a | mat 1: colsum->s_b | mat 2: fp4 c4.
// grid (256, 3), block 256, 16 rows/block (4/wave, 2 batches of 2).
// ---------------------------------------------------------------------------
__global__ __launch_bounds__(256) void normalize_colsum_kernel(
    const float* __restrict__ src, const float* __restrict__ bc,
    const float* __restrict__ raw,
    unsigned int* __restrict__ a4, unsigned int* __restrict__ c4,
    float* __restrict__ s_a, float* __restrict__ s_b) {
  const int mat = blockIdx.y;
  const int tid = threadIdx.x;
  const int lane = tid & 63;
  const int wave = tid >> 6;
  const float* base = (mat == 0) ? src : ((mat == 1) ? bc : raw);
  unsigned int* q4 = (mat == 0) ? a4 : c4;  // unused for mat 1

  // acc[4c+i] accumulates column 4*lane + 256*c + i  (c<8, i<4)
  float acc[32];
  #pragma unroll
  for (int i = 0; i < 32; i++) acc[i] = 0.f;

  #pragma unroll 1
  for (int b = 0; b < 2; b++) {
    const int rowA = blockIdx.x * 16 + wave * 4 + b * 2;
    const float4* rpA = (const float4*)(base + (size_t)rowA * DD);
    const float4* rpB = (const float4*)(base + (size_t)(rowA + 1) * DD);

    float4 vA[8], vB[8];
    #pragma unroll
    for (int c = 0; c < 8; c++) {
      vA[c] = rpA[lane + 64 * c];
      vB[c] = rpB[lane + 64 * c];
    }
    float ssA = 0.f, ssB = 0.f;
    #pragma unroll
    for (int c = 0; c < 8; c++) {
      ssA += vA[c].x * vA[c].x + vA[c].y * vA[c].y +
             vA[c].z * vA[c].z + vA[c].w * vA[c].w;
      ssB += vB[c].x * vB[c].x + vB[c].y * vB[c].y +
             vB[c].z * vB[c].z + vB[c].w * vB[c].w;
    }
    #pragma unroll
    for (int off = 1; off < 64; off <<= 1) {
      ssA += __shfl_xor(ssA, off, 64);
      ssB += __shfl_xor(ssB, off, 64);
    }
    const float sinvA = rsqrtf(ssA);
    const float sinvB = rsqrtf(ssB);

    if (mat != 2) {
      #pragma unroll
      for (int c = 0; c < 8; c++) {
        acc[c * 4 + 0] += (vA[c].x * sinvA + vB[c].x * sinvB);
        acc[c * 4 + 1] += (vA[c].y * sinvA + vB[c].y * sinvB);
        acc[c * 4 + 2] += (vA[c].z * sinvA + vB[c].z * sinvB);
        acc[c * 4 + 3] += (vA[c].w * sinvA + vB[c].w * sinvB);
      }
    }
    if (mat != 1) {
      const float s4A = sinvA * QS4;
      const float s4B = sinvB * QS4;
      uintx4 wA, wB;
      #pragma unroll
      for (int d = 0; d < 4; d++) {
        wA[d] = pack8_fp4(vA[2 * d], vA[2 * d + 1], s4A);
        wB[d] = pack8_fp4(vB[2 * d], vB[2 * d + 1], s4B);
      }
      *(uintx4*)&q4[rowA * 256 + lane * 4] = wA;
      *(uintx4*)&q4[(rowA + 1) * 256 + lane * 4] = wB;
    }
  }
  if (mat == 2) return;  // uniform per block — no divergent barrier

  __shared__ float lsum[4][2048];
  #pragma unroll
  for (int c = 0; c < 8; c++)
    *(floatx4*)&lsum[wave][4 * lane + 256 * c] =
        floatx4{acc[4 * c], acc[4 * c + 1], acc[4 * c + 2], acc[4 * c + 3]};
  __syncthreads();
  float* dst = (mat == 0) ? s_a : s_b;
  #pragma unroll
  for (int k = 0; k < 8; k++) {
    const int col = tid + 256 * k;
    atomicAdd(&dst[col],
              lsum[0][col] + lsum[1][col] + lsum[2][col] + lsum[3][col]);
  }
}

// ---------------------------------------------------------------------------
// Kernel 2: MX-fp4 MFMA GEMM a_n @ c_n^T with fused sum(exp(sim/T)) epilogue.
// r22: 256x256 TILE (the one big untried gemm lever). Rationale: MFMA pipe
// time ~6.6us vs ~27us wall; floors LDS ~11us (768MB: 2x operand overdraw),
// L2 service ~7.8us (268MB). 256^2 tile halves global service (268->128MB)
// and cuts LDS to 512MB (3x overdraw). History: this kernel responds to
// service-traffic cuts (fp8->fp4 536->268MB gave 41->27us).
// All verified components carried over UNCHANGED: same XOR source-swizzle
// (^(r&7), row-count independent), same staging idiom (8-row x 128B windows,
// wave-uniform LDS base + lane*16), same fragment math, bijective XCD chunks
// (4br x 8bc per XCD -> 3MB L2 set). LDS 128KB; acc[4][2]x16=128 VGPR +
// per-s operands ~190 < 256 cap (launch_bounds(512,2) => 2 waves/SIMD).
// grid (16,16) = 256 blocks (1/CU), block 512 (8 waves: 2 row-halves x
// 4 col-groups; per wave 128x64 output).
// ---------------------------------------------------------------------------
__global__ __launch_bounds__(512, 2) void gemm_expsum_kernel(
    const unsigned char* __restrict__ a4, const unsigned char* __restrict__ c4,
    float* __restrict__ S_part) {
  __shared__ unsigned char As[2][256 * 128];  // [buf][row][chunk^(row&7)]
  __shared__ unsigned char Cs[2][256 * 128];
  const int tid = threadIdx.x;
  const int lane = tid & 63;
  const int wave = tid >> 6;      // 0..7
  const int wr = wave >> 2;       // row half (128 rows)
  const int wc = wave & 3;        // col group (64 cols)
  const int half = lane >> 5;     // k-half selector within a k-step (K=64)
  const int l32 = lane & 31;

  // XCD-chunked swizzle (bijective: 256 = 8 chunks x 32 blocks; 4br x 8bc)
  const int lin = blockIdx.y * 16 + blockIdx.x;
  const int xcd = lin & 7;        // HW assigns lin -> XCD round-robin
  const int idx = lin >> 3;       // 0..31 within this XCD's chunk
  const int br = (xcd >> 1) * 4 + (idx >> 3);   // 0..15 (256-row panel)
  const int bc = (xcd & 1) * 8 + (idx & 7);     // 0..15 (256-col panel)

  floatx16 acc[4][2] = {};

  // staging: per matrix+buffer, 32 windows of 1KB (8 rows x 128B); 4/wave.
  // fp4 row = 1024B; ktile kt covers row bytes [kt*128, kt*128+128).
  const int wrow = lane >> 3;
  const int csrc = (lane & 7) ^ (wrow & 7);
  const unsigned char* gA[4];
  const unsigned char* gC[4];
  int ldsOff[4];
  #pragma unroll
  for (int q = 0; q < 4; q++) {
    const int m = wave * 4 + q;       // 0..31
    const int row = m * 8 + wrow;     // 0..255
    gA[q] = a4 + (size_t)(br * 256 + row) * 1024 + csrc * 16;
    gC[q] = c4 + (size_t)(bc * 256 + row) * 1024 + csrc * 16;
    ldsOff[q] = m * 1024;
  }

  // prologue: stage ktile 0 into buffer 0
  #pragma unroll
  for (int q = 0; q < 4; q++) {
    async_copy16(gA[q], &As[0][ldsOff[q]]);
    async_copy16(gC[q], &Cs[0][ldsOff[q]]);
    gA[q] += 128; gC[q] += 128;
  }

  const int NKT = DD / 256;  // 8 ktiles
  #pragma unroll 2
  for (int kt = 0; kt < NKT; kt++) {
    const int cur = kt & 1;
    __syncthreads();  // drains vmcnt: ktile-kt stage (issued one body ago)

    if (kt < NKT - 1) {  // prefetch kt+1 into the other buffer
      #pragma unroll
      for (int q = 0; q < 4; q++) {
        async_copy16(gA[q], &As[cur ^ 1][ldsOff[q]]);
        async_copy16(gC[q], &Cs[cur ^ 1][ldsOff[q]]);
        gA[q] += 128; gC[q] += 128;
      }
    }

    // fragments per k-step s (64 k-elems = 32B/row): lane(half,l32) reads
    // 16B at logical chunk s*2+half (physical ^(r&7)). Loaded per-s to
    // bound register liveness (acc alone is 128 VGPR).
    #pragma unroll
    for (int s = 0; s < 4; s++) {
      int4v af[4], bf[2];
      #pragma unroll
      for (int i = 0; i < 4; i++) {
        const int r = wr * 128 + i * 32 + l32;
        const int pc = (s * 2 + half) ^ (r & 7);
        af[i] = *(const int4v*)&As[cur][r * 128 + pc * 16];
      }
      #pragma unroll
      for (int j = 0; j < 2; j++) {
        const int r = wc * 64 + j * 32 + l32;
        const int pc = (s * 2 + half) ^ (r & 7);
        bf[j] = *(const int4v*)&Cs[cur][r * 128 + pc * 16];
      }
      #pragma unroll
      for (int i = 0; i < 4; i++) {
        const int8v a8v = int8v{af[i][0], af[i][1], af[i][2], af[i][3],
                                0, 0, 0, 0};
        #pragma unroll
        for (int j = 0; j < 2; j++) {
          const int8v b8v = int8v{bf[j][0], bf[j][1], bf[j][2], bf[j][3],
                                  0, 0, 0, 0};
          acc[i][j] = __builtin_amdgcn_mfma_scale_f32_32x32x64_f8f6f4(
              a8v, b8v, acc[i][j], 4 /*cbsz: fp4*/, 4 /*blgp: fp4*/,
              0, 0x7F7F7F7F, 0, 0x7F7F7F7F /*E8M0 identity scales*/);
        }
      }
    }
  }

  // epilogue: sum exp(sim/T) over this block's 256x256 tile; acc = 4096*sim.
  float local = 0.f;
  #pragma unroll
  for (int i = 0; i < 4; i++)
    #pragma unroll
    for (int j = 0; j < 2; j++)
      #pragma unroll
      for (int r = 0; r < 16; r++)
        local += __expf(acc[i][j][r] * ACC4_TO_LOGIT);
  #pragma unroll
  for (int off = 32; off > 0; off >>= 1) local += __shfl_down(local, off, 64);
  __shared__ float red[8];
  if (lane == 0) red[wave] = local;
  __syncthreads();
  if (tid == 0) {
    float t = 0.f;
    #pragma unroll
    for (int w = 0; w < 8; w++) t += red[w];
    S_part[br * 16 + bc] = t;
  }
}

// ---------------------------------------------------------------------------
// Kernel 3: tiny finalize. Separate dispatch => kernel-boundary coherence,
// so plain (non-atomic) reads of s_a/s_b/S_part are safe. 1 block.
// S_part now has 256 entries (one per 256^2 gemm block).
// ---------------------------------------------------------------------------
__global__ __launch_bounds__(256) void finalize_kernel(
    const float* __restrict__ s_a, const float* __restrict__ s_b,
    const float* __restrict__ S_part, float* __restrict__ out) {
  const int tid = threadIdx.x;
  float dot = 0.f;
  #pragma unroll
  for (int k = 0; k < 8; k++)
    dot += s_a[tid + 256 * k] * s_b[tid + 256 * k];
  float se = S_part[tid];
  #pragma unroll
  for (int off = 32; off > 0; off >>= 1) {
    dot += __shfl_down(dot, off, 64);
    se  += __shfl_down(se, off, 64);
  }
  __shared__ float redd[4], reds[4];
  if ((tid & 63) == 0) { redd[tid >> 6] = dot; reds[tid >> 6] = se; }
  __syncthreads();
  if (tid == 0) {
    const float dt = redd[0] + redd[1] + redd[2] + redd[3];
    const float st = reds[0] + reds[1] + reds[2] + reds[3];
    // loss = log(sum exp(sim_neg/T)) - mean(sim_pos)/T
    out[0] = logf(st) - dt * (INV_T / ((float)NR * (float)NR));
  }
}

extern "C" void kernel_launch(void* const* d_in, const int* in_sizes, int n_in,
                              void* d_out, int out_size, void* d_ws, size_t ws_size,
                              hipStream_t stream) {
  const float* src = (const float*)d_in[0];
  const float* bc  = (const float*)d_in[1];
  const float* raw = (const float*)d_in[2];

  char* ws = (char*)d_ws;
  unsigned int* a4 = (unsigned int*)ws;                             // 4 MiB
  unsigned int* c4 = (unsigned int*)(ws + (size_t)4 * 1024 * 1024); // 4 MiB
  float* zb  = (float*)(ws + (size_t)8 * 1024 * 1024);  // s_a | s_b (16 KiB)
  float* s_a = zb;
  float* s_b = zb + DD;
  float* S_part = (float*)(ws + (size_t)8 * 1024 * 1024 + 32 * 1024);  // 1 KiB

  zero_kernel<<<1, 256, 0, stream>>>(zb);
  normalize_colsum_kernel<<<dim3(NR / 16, 3), 256, 0, stream>>>(
      src, bc, raw, a4, c4, s_a, s_b);
  gemm_expsum_kernel<<<dim3(16, 16), 512, 0, stream>>>(
      (const unsigned char*)a4, (const unsigned char*)c4, S_part);
  finalize_kernel<<<1, 256, 0, stream>>>(s_a, s_b, S_part, (float*)d_out);
}